// Round 9
// baseline (136.786 us; speedup 1.0000x reference)
//
#include <hip/hip_runtime.h>

using u32 = unsigned int;

typedef __attribute__((ext_vector_type(8))) _Float16 f16x8;
typedef __attribute__((ext_vector_type(4))) float    f32x4;

// ---------------------------------------------------------------------------
// prep: WcatT[n][kk] = s(i,kb) * W[c][(i^kb)*256 + u]   (f16, 1024x1024)
// sign bits packed: bit (4*i + kb) of 0x3950
// ---------------------------------------------------------------------------
__global__ __launch_bounds__(256) void build_wcatT(const float* __restrict__ W,
                                                   _Float16* __restrict__ Wt) {
    int t  = blockIdx.x * 256 + threadIdx.x;
    int n  = t >> 10, kk = t & 1023;
    int kb = n >> 8,  u  = n & 255;
    int i  = kk >> 8, c  = kk & 255;
    int j  = i ^ kb;
    float v = W[c * 1024 + j * 256 + u];
    if ((0x3950u >> (i * 4 + kb)) & 1u) v = -v;
    Wt[t] = (_Float16)v;
}

// ---------------------------------------------------------------------------
// GEMM: A (x, f32) loaded DIRECTLY global->reg as MFMA fragments (saddr +
// per-lane voffset), cvt f32->f16 in-register. No cast kernel, no A-LDS.
// B via R7-proven gload_lds path (pre-swizzled source, 0-conflict reads).
//   M=16384 N=1024 K=1024.  BM=256 BN=128 BK=64, 16 K-tiles.
//   8 waves (4M x 2N), acc[4][4]; LDS = B only, 3 x 16 KB.
//   One barrier/tile; counted vmcnt: enter tile T with [A(T)x16, B(T+1)x2].
// ---------------------------------------------------------------------------
__device__ __forceinline__ void async16(const void* g, void* l) {
    __builtin_amdgcn_global_load_lds((const __attribute__((address_space(1))) u32*)g,
                                     (__attribute__((address_space(3))) u32*)l,
                                     16, 0, 0);
}

#define BARRIER() do { asm volatile("" ::: "memory"); \
                       __builtin_amdgcn_s_barrier(); \
                       asm volatile("" ::: "memory"); } while (0)

#define VMW(n)  asm volatile("s_waitcnt vmcnt(" #n ")" ::: "memory")
#define SB0()   __builtin_amdgcn_sched_barrier(0)

// global_load_dwordx4 dst, voffset(VGPR), sbase(SGPR pair) + literal offset
#define GLS(dst, voff, sb, OFF) \
    asm volatile("global_load_dwordx4 %0, %1, %2 offset:" #OFF \
                 : "=v"(dst) : "v"(voff), "s"(sb))

#define MFMA(av, bv, c) __builtin_amdgcn_mfma_f32_16x16x32_f16(av, bv, c, 0, 0, 0)

#define MM16() do { \
    __builtin_amdgcn_s_setprio(1); \
    acc[0][0]=MFMA(af0,bf0,acc[0][0]); acc[0][1]=MFMA(af0,bf1,acc[0][1]); \
    acc[0][2]=MFMA(af0,bf2,acc[0][2]); acc[0][3]=MFMA(af0,bf3,acc[0][3]); \
    acc[1][0]=MFMA(af1,bf0,acc[1][0]); acc[1][1]=MFMA(af1,bf1,acc[1][1]); \
    acc[1][2]=MFMA(af1,bf2,acc[1][2]); acc[1][3]=MFMA(af1,bf3,acc[1][3]); \
    acc[2][0]=MFMA(af2,bf0,acc[2][0]); acc[2][1]=MFMA(af2,bf1,acc[2][1]); \
    acc[2][2]=MFMA(af2,bf2,acc[2][2]); acc[2][3]=MFMA(af2,bf3,acc[2][3]); \
    acc[3][0]=MFMA(af3,bf0,acc[3][0]); acc[3][1]=MFMA(af3,bf1,acc[3][1]); \
    acc[3][2]=MFMA(af3,bf2,acc[3][2]); acc[3][3]=MFMA(af3,bf3,acc[3][3]); \
    __builtin_amdgcn_s_setprio(0); \
    __builtin_amdgcn_sched_barrier(0); \
} while (0)

// issue 8 A-loads for K-tile U, k-half 0 (cols (U&3)*64 + [0,32)) into set R
#define ISSUE_K0(U, R) do { \
    const float* _sb = A + (size_t)m0 * 256 + (size_t)((U) >> 2) * 4194304 + ((U) & 3) * 64; \
    GLS(R##0, voff0, _sb, 0);  GLS(R##1, voff0, _sb, 16); \
    GLS(R##2, voff1, _sb, 0);  GLS(R##3, voff1, _sb, 16); \
    GLS(R##4, voff2, _sb, 0);  GLS(R##5, voff2, _sb, 16); \
    GLS(R##6, voff3, _sb, 0);  GLS(R##7, voff3, _sb, 16); \
} while (0)

// k-half 1: +32 f32 = +128 bytes
#define ISSUE_K1(U, R) do { \
    const float* _sb = A + (size_t)m0 * 256 + (size_t)((U) >> 2) * 4194304 + ((U) & 3) * 64; \
    GLS(R##0, voff0, _sb, 128); GLS(R##1, voff0, _sb, 144); \
    GLS(R##2, voff1, _sb, 128); GLS(R##3, voff1, _sb, 144); \
    GLS(R##4, voff2, _sb, 128); GLS(R##5, voff2, _sb, 144); \
    GLS(R##6, voff3, _sb, 128); GLS(R##7, voff3, _sb, 144); \
} while (0)

// cvt raw set R (8 x f32x4) -> af0..af3 (4 x f16x8)
#define CVTSET(R) do { \
    af0[0]=(_Float16)R##0[0]; af0[1]=(_Float16)R##0[1]; af0[2]=(_Float16)R##0[2]; af0[3]=(_Float16)R##0[3]; \
    af0[4]=(_Float16)R##1[0]; af0[5]=(_Float16)R##1[1]; af0[6]=(_Float16)R##1[2]; af0[7]=(_Float16)R##1[3]; \
    af1[0]=(_Float16)R##2[0]; af1[1]=(_Float16)R##2[1]; af1[2]=(_Float16)R##2[2]; af1[3]=(_Float16)R##2[3]; \
    af1[4]=(_Float16)R##3[0]; af1[5]=(_Float16)R##3[1]; af1[6]=(_Float16)R##3[2]; af1[7]=(_Float16)R##3[3]; \
    af2[0]=(_Float16)R##4[0]; af2[1]=(_Float16)R##4[1]; af2[2]=(_Float16)R##4[2]; af2[3]=(_Float16)R##4[3]; \
    af2[4]=(_Float16)R##5[0]; af2[5]=(_Float16)R##5[1]; af2[6]=(_Float16)R##5[2]; af2[7]=(_Float16)R##5[3]; \
    af3[0]=(_Float16)R##6[0]; af3[1]=(_Float16)R##6[1]; af3[2]=(_Float16)R##6[2]; af3[3]=(_Float16)R##6[3]; \
    af3[4]=(_Float16)R##7[0]; af3[5]=(_Float16)R##7[1]; af3[6]=(_Float16)R##7[2]; af3[7]=(_Float16)R##7[3]; \
} while (0)

// stage B K-tile U into LDS buffer BI (2 gload_lds; source pre-swizzled)
#define STAGE_B(U, BI) do { \
    const _Float16* _s = gB + (U) * 64; \
    _Float16* _d = ldsB + (BI) * 8192 + tid * 8; \
    async16(_s, _d); \
    async16(_s + 65536, _d + 4096); \
} while (0)

#define TILE(T, BI, G1, G2, DO_NEXT, DO_STAGE, G3, DO_BAR) do { \
    const _Float16* Bb = ldsB + (BI) * 8192; \
    f16x8 af0, af1, af2, af3; \
    G1; SB0(); \
    CVTSET(p); \
    if (DO_NEXT) { ISSUE_K0((T) + 1, p); } \
    SB0(); \
    { f16x8 bf0 = *(const f16x8*)(Bb + bRow + bc0); \
      f16x8 bf1 = *(const f16x8*)(Bb + bRow + 1024 + bc0); \
      f16x8 bf2 = *(const f16x8*)(Bb + bRow + 2048 + bc0); \
      f16x8 bf3 = *(const f16x8*)(Bb + bRow + 3072 + bc0); \
      MM16(); } \
    G2; SB0(); \
    CVTSET(q); \
    if (DO_NEXT) { ISSUE_K1((T) + 1, q); } \
    SB0(); \
    { f16x8 bf0 = *(const f16x8*)(Bb + bRow + bc1); \
      f16x8 bf1 = *(const f16x8*)(Bb + bRow + 1024 + bc1); \
      f16x8 bf2 = *(const f16x8*)(Bb + bRow + 2048 + bc1); \
      f16x8 bf3 = *(const f16x8*)(Bb + bRow + 3072 + bc1); \
      MM16(); } \
    if (DO_STAGE) { STAGE_B((T) + 2, ((T) + 2) % 3); } \
    G3; \
    if (DO_BAR) { BARRIER(); } \
} while (0)

__global__ __launch_bounds__(512, 2) void ga_gemm(const float* __restrict__ A,    // x f32
                                                  const _Float16* __restrict__ Bt,// WcatT
                                                  const float*  __restrict__ bias,
                                                  float* __restrict__ out) {
    __shared__ _Float16 ldsB[3 * 8192] __attribute__((aligned(16)));  // 48 KiB

    const int tid  = threadIdx.x;
    const int lane = tid & 63;
    const int wid  = tid >> 6;          // 0..7
    const int wm   = wid >> 1;          // 0..3  (64-row strip of BM=256)
    const int wn   = wid & 1;           // 0..1  (64-col strip of BN=128)
    const int l15  = lane & 15;
    const int lg   = lane >> 4;

    // XCD swizzle: 512 blocks; each XCD gets 8 consecutive m-panels x 8 nt
    const int bid = blockIdx.x;
    const int swz = (bid & 7) * 64 + (bid >> 3);
    const int mt  = swz >> 3, nt = swz & 7;   // 64 m-tiles x 8 n-tiles
    const int m0  = mt * 256, n0 = nt * 128;

    // A per-lane byte voffsets (loop-invariant): row_local*1024 + lg*32
    const u32 voff0 = (u32)(((wm * 64 +  0 + l15) * 256 + lg * 8) * 4);
    const u32 voff1 = (u32)(((wm * 64 + 16 + l15) * 256 + lg * 8) * 4);
    const u32 voff2 = (u32)(((wm * 64 + 32 + l15) * 256 + lg * 8) * 4);
    const u32 voff3 = (u32)(((wm * 64 + 48 + l15) * 256 + lg * 8) * 4);

    // B staging source (pre-swizzled chunk; linear LDS dest)
    const int brow = tid >> 3;
    const int blc  = (tid & 7) ^ (brow & 7);
    const _Float16* gB = Bt + (size_t)(n0 + brow) * 1024 + blc * 8;

    // B fragment reads: row = wn*64 + fn*16 + l15; phys chunk = log ^ (row&7)
    const int bRow = wn * 4096 + l15 * 64;
    const int bc0  = ((lg)     ^ (l15 & 7)) * 8;
    const int bc1  = ((4 + lg) ^ (l15 & 7)) * 8;

    f32x4 acc[4][4] = {};
    f32x4 p0, p1, p2, p3, p4, p5, p6, p7;
    f32x4 q0, q1, q2, q3, q4, q5, q6, q7;

    // prologue: A(0) both halves + B(0), B(1); drain all but B(1)
    ISSUE_K0(0, p);
    ISSUE_K1(0, q);
    STAGE_B(0, 0);
    STAGE_B(1, 1);
    VMW(2);
    BARRIER();

    TILE( 0, 0, VMW(10), VMW(10), 1, 1, VMW(18), 1);
    TILE( 1, 1, VMW(10), VMW(10), 1, 1, VMW(18), 1);
    TILE( 2, 2, VMW(10), VMW(10), 1, 1, VMW(18), 1);
    TILE( 3, 0, VMW(10), VMW(10), 1, 1, VMW(18), 1);
    TILE( 4, 1, VMW(10), VMW(10), 1, 1, VMW(18), 1);
    TILE( 5, 2, VMW(10), VMW(10), 1, 1, VMW(18), 1);
    TILE( 6, 0, VMW(10), VMW(10), 1, 1, VMW(18), 1);
    TILE( 7, 1, VMW(10), VMW(10), 1, 1, VMW(18), 1);
    TILE( 8, 2, VMW(10), VMW(10), 1, 1, VMW(18), 1);
    TILE( 9, 0, VMW(10), VMW(10), 1, 1, VMW(18), 1);
    TILE(10, 1, VMW(10), VMW(10), 1, 1, VMW(18), 1);
    TILE(11, 2, VMW(10), VMW(10), 1, 1, VMW(18), 1);
    TILE(12, 0, VMW(10), VMW(10), 1, 1, VMW(18), 1);
    TILE(13, 1, VMW(10), VMW(10), 1, 1, VMW(18), 1);
    TILE(14, 2, VMW(10), VMW(10), 1, 0, VMW(16), 1);   // no B(16); drain B(15)
    TILE(15, 0, VMW(8),  VMW(0),  0, 0, (void)0, 0);   // final tile

    // epilogue: C/D layout col=lane&15 (n), row=(lane>>4)*4+rr (m)
    const int nbase = nt * 128 + wn * 64;      // 64-aligned, within one blade
    const int kb    = nbase >> 8;              // output blade
    const int ub    = (nbase & 255) + l15;     // col within blade
    float bv[4];
#pragma unroll
    for (int fn = 0; fn < 4; ++fn) bv[fn] = bias[nbase + fn * 16 + l15];
#pragma unroll
    for (int fm = 0; fm < 4; ++fm) {
        const int m = m0 + wm * 64 + fm * 16 + lg * 4;
#pragma unroll
        for (int rr = 0; rr < 4; ++rr) {
            float* op = out + ((size_t)kb * 16384 + m + rr) * 256 + ub;
#pragma unroll
            for (int fn = 0; fn < 4; ++fn)
                op[fn * 16] = acc[fm][fn][rr] + bv[fn];
        }
    }
}

// ---------------------------------------------------------------------------
extern "C" void kernel_launch(void* const* d_in, const int* in_sizes, int n_in,
                              void* d_out, int out_size, void* d_ws, size_t ws_size,
                              hipStream_t stream) {
    (void)in_sizes; (void)n_in; (void)out_size; (void)ws_size;
    const float* x = (const float*)d_in[0];   // (65536, 256)
    const float* W = (const float*)d_in[1];   // (256, 1024)
    const float* b = (const float*)d_in[2];   // (1024,)
    float* out = (float*)d_out;               // (65536, 256)

    _Float16* Wt = (_Float16*)d_ws;           // 2 MB

    build_wcatT<<<4096, 256, 0, stream>>>(W, Wt);
    ga_gemm<<<512, 512, 0, stream>>>(x, Wt, b, out);
}

// Round 10
// 53.108 us; speedup vs baseline: 2.5756x; 2.5756x over previous
//
#include <hip/hip_runtime.h>

using u32 = unsigned int;

typedef __attribute__((ext_vector_type(8))) _Float16 f16x8;
typedef __attribute__((ext_vector_type(4))) float    f32x4;

// ---------------------------------------------------------------------------
// prep: WcatT[n][kk] = s(i,kb) * W[c][(i^kb)*256 + u]   (f16, 1024x1024)
// sign bits packed: bit (4*i + kb) of 0x3950
// ---------------------------------------------------------------------------
__global__ __launch_bounds__(256) void build_wcatT(const float* __restrict__ W,
                                                   _Float16* __restrict__ Wt) {
    int t  = blockIdx.x * 256 + threadIdx.x;
    int n  = t >> 10, kk = t & 1023;
    int kb = n >> 8,  u  = n & 255;
    int i  = kk >> 8, c  = kk & 255;
    int j  = i ^ kb;
    float v = W[c * 1024 + j * 256 + u];
    if ((0x3950u >> (i * 4 + kb)) & 1u) v = -v;
    Wt[t] = (_Float16)v;
}

// ---------------------------------------------------------------------------
// GEMM with fused f32->f16 A-cast (R4 skeleton + surgical fixes):
//   M=16384 N=1024 K=1024. 256x256 tile, BK=32, 4 LDS buffers (128KB),
//   8 waves (2M x 4N). A: reg-staged 4-threads/row (16-line instrs),
//   WRITE_A hoisted before MM2 (overlap), steady VMW(6) exact ledger.
//   B: gload_lds, pre-swizzled source (R4-proven, 0 conflicts).
// ---------------------------------------------------------------------------
__device__ __forceinline__ void async16(const void* g, void* l) {
    __builtin_amdgcn_global_load_lds((const __attribute__((address_space(1))) u32*)g,
                                     (__attribute__((address_space(3))) u32*)l,
                                     16, 0, 0);
}

#define BARRIER() do { asm volatile("" ::: "memory"); \
                       __builtin_amdgcn_s_barrier(); \
                       asm volatile("" ::: "memory"); } while (0)

#define VMW(n)  asm volatile("s_waitcnt vmcnt(" #n ")" ::: "memory")
#define LGKM0() asm volatile("s_waitcnt lgkmcnt(0)" ::: "memory")
#define SB0()   __builtin_amdgcn_sched_barrier(0)

#define GL16(dst, ptr, off) \
    asm volatile("global_load_dwordx4 %0, %1, off offset:" #off \
                 : "=v"(dst) : "v"(ptr))

#define MFMA(av, bv, c) __builtin_amdgcn_mfma_f32_16x16x32_f16(av, bv, c, 0, 0, 0)

#define PHASE_MFMA(f0, f1, f2, f3) do { \
    __builtin_amdgcn_s_setprio(1); \
    acc[f0][0]=MFMA(a0,b0,acc[f0][0]); acc[f0][1]=MFMA(a0,b1,acc[f0][1]); \
    acc[f0][2]=MFMA(a0,b2,acc[f0][2]); acc[f0][3]=MFMA(a0,b3,acc[f0][3]); \
    acc[f1][0]=MFMA(a1,b0,acc[f1][0]); acc[f1][1]=MFMA(a1,b1,acc[f1][1]); \
    acc[f1][2]=MFMA(a1,b2,acc[f1][2]); acc[f1][3]=MFMA(a1,b3,acc[f1][3]); \
    acc[f2][0]=MFMA(a2,b0,acc[f2][0]); acc[f2][1]=MFMA(a2,b1,acc[f2][1]); \
    acc[f2][2]=MFMA(a2,b2,acc[f2][2]); acc[f2][3]=MFMA(a2,b3,acc[f2][3]); \
    acc[f3][0]=MFMA(a3,b0,acc[f3][0]); acc[f3][1]=MFMA(a3,b1,acc[f3][1]); \
    acc[f3][2]=MFMA(a3,b2,acc[f3][2]); acc[f3][3]=MFMA(a3,b3,acc[f3][3]); \
    __builtin_amdgcn_s_setprio(0); \
    __builtin_amdgcn_sched_barrier(0); \
} while (0)

// B K-tile U -> buf BI (2 x gload_lds/thread, source pre-swizzled)
#define STAGE_B(U, BI) do { \
    const int _b = (BI) * 16384 + 8192; \
    const int _g = (U) * 32; \
    async16(gB0 + _g, lds + _b + tid * 8); \
    async16(gB1 + _g, lds + _b + 4096 + tid * 8); \
} while (0)

// A K-tile U: 2 slots (rows ar, ar+128), contiguous 32B f32 per slot
#define ISSUE_A(U, d0, d1, d2, d3) do { \
    const float* _p = pA + (size_t)((U) >> 3) * 4194304 + ((U) & 7) * 32; \
    GL16(d0, _p, 0); GL16(d1, _p, 16); \
    const float* _q = _p + 32768; \
    GL16(d2, _q, 0); GL16(d3, _q, 16); \
} while (0)

// cvt 16 f32 -> 2 swizzled ds_write_b128 (slot0 -> aw0, slot1 -> aw0+4096)
#define WRITE_A(BI, s0, s1, s2, s3) do { \
    f16x8 h0, h1; \
    h0[0]=(_Float16)(s0)[0]; h0[1]=(_Float16)(s0)[1]; h0[2]=(_Float16)(s0)[2]; h0[3]=(_Float16)(s0)[3]; \
    h0[4]=(_Float16)(s1)[0]; h0[5]=(_Float16)(s1)[1]; h0[6]=(_Float16)(s1)[2]; h0[7]=(_Float16)(s1)[3]; \
    h1[0]=(_Float16)(s2)[0]; h1[1]=(_Float16)(s2)[1]; h1[2]=(_Float16)(s2)[2]; h1[3]=(_Float16)(s2)[3]; \
    h1[4]=(_Float16)(s3)[0]; h1[5]=(_Float16)(s3)[1]; h1[6]=(_Float16)(s3)[2]; h1[7]=(_Float16)(s3)[3]; \
    _Float16* _wp = lds + (BI) * 16384 + aw0; \
    *(f16x8*)(_wp) = h0; \
    *(f16x8*)(_wp + 4096) = h1; \
} while (0)

// tile T: [reads1+ISSUE_A(T+3); B; MM1; B; reads2+STAGE_B(T+2);
//          GATE; SB0; WRITE_A(T+2); B; MM2; LGKM0; B]
#define TILE(T, DO_ISSUE, I0,I1,I2,I3, DO_STAGE, DO_WRITE, W0,W1,W2,W3, GATE) do { \
    const _Float16* Ab = lds + ((T) & 3) * 16384; \
    const _Float16* Bb = Ab + 8192; \
    f16x8 a0, a1, a2, a3, b0, b1, b2, b3; \
    a0 = *(const f16x8*)(Ab + aoff);        a1 = *(const f16x8*)(Ab + aoff + 512); \
    a2 = *(const f16x8*)(Ab + aoff + 1024); a3 = *(const f16x8*)(Ab + aoff + 1536); \
    b0 = *(const f16x8*)(Bb + boff);        b1 = *(const f16x8*)(Bb + boff + 512); \
    b2 = *(const f16x8*)(Bb + boff + 1024); b3 = *(const f16x8*)(Bb + boff + 1536); \
    if (DO_ISSUE) { ISSUE_A((T) + 3, I0, I1, I2, I3); } \
    BARRIER(); \
    PHASE_MFMA(0, 1, 2, 3); \
    BARRIER(); \
    a0 = *(const f16x8*)(Ab + aoff + 2048); a1 = *(const f16x8*)(Ab + aoff + 2560); \
    a2 = *(const f16x8*)(Ab + aoff + 3072); a3 = *(const f16x8*)(Ab + aoff + 3584); \
    if (DO_STAGE) { STAGE_B((T) + 2, ((T) + 2) & 3); } \
    GATE; \
    SB0(); \
    if (DO_WRITE) { WRITE_A((((T) + 2) & 3), W0, W1, W2, W3); } \
    BARRIER(); \
    PHASE_MFMA(4, 5, 6, 7); \
    LGKM0(); \
    BARRIER(); \
} while (0)

__global__ __launch_bounds__(512, 2) void ga_gemm(const float* __restrict__ A,    // x f32
                                                  const _Float16* __restrict__ Bt,// WcatT
                                                  const float*  __restrict__ bias,
                                                  float* __restrict__ out) {
    __shared__ _Float16 lds[4 * 16384] __attribute__((aligned(16)));  // 128 KiB

    const int tid  = threadIdx.x;
    const int lane = tid & 63;
    const int wid  = tid >> 6;
    const int wm   = wid >> 2;          // 0..1
    const int wn   = wid & 3;           // 0..3
    const int l15  = lane & 15;
    const int lg   = lane >> 4;

    // XCD-aware bijective swizzle: 256 blocks, 8 XCDs, 32 contiguous each
    const int bid = blockIdx.x;
    const int swz = (bid & 7) * 32 + (bid >> 3);
    const int mt  = swz >> 2, nt = swz & 3;
    const int m0  = mt * 256,  n0 = nt * 256;

    // A staging: 4 threads/row; slots (ar, ac) and (ar+128, ac), 32B each
    const int ar = tid >> 2, ac = tid & 3;
    const float* pA = A + (size_t)(m0 + ar) * 256 + ac * 8;
    const int aw0 = ar * 32 + (ac ^ ((ar >> 1) & 3)) * 8;   // f16 units

    // B staging (slot s -> row s>>2, chunk s&3; source pre-swizzled)
    const int s1 = 512 + tid;
    const int r0 = tid >> 2,  r1 = s1 >> 2;
    const int g0 = (tid & 3) ^ ((r0 >> 1) & 3);
    const int g1 = (s1 & 3)  ^ ((r1 >> 1) & 3);
    const _Float16* gB0 = Bt + (size_t)(n0 + r0) * 1024 + g0 * 8;
    const _Float16* gB1 = Bt + (size_t)(n0 + r1) * 1024 + g1 * 8;

    // ds_read fragment offsets (f16 units), swizzled chunk per thread
    const int sc   = lg ^ ((l15 >> 1) & 3);
    const int aoff = (wm * 128 + l15) * 32 + sc * 8;
    const int boff = (wn * 64  + l15) * 32 + sc * 8;

    f32x4 acc[8][4] = {};
    f32x4 u0, u1, u2, u3, v0, v1, v2, v3;

    // prologue: A(0)->u, A(1)->v, B(0), B(1); write A(0),A(1); issue A(2)->u
    ISSUE_A(0, u0, u1, u2, u3);
    ISSUE_A(1, v0, v1, v2, v3);
    STAGE_B(0, 0);
    STAGE_B(1, 1);
    VMW(8);  SB0();                  // A(0) landed
    WRITE_A(0, u0, u1, u2, u3);
    VMW(4);  SB0();                  // A(1) landed
    WRITE_A(1, v0, v1, v2, v3);
    LGKM0();                         // ds_writes sourcing u consumed
    ISSUE_A(2, u0, u1, u2, u3);
    VMW(6);                          // B(0) landed (leaves B(1), A(2))
    LGKM0();
    BARRIER();

    // steady: T even -> issue v / write u; T odd -> issue u / write v
    for (int t = 0; t < 28; t += 2) {
        TILE(t,     1, v0,v1,v2,v3, 1, 1, u0,u1,u2,u3, VMW(6));
        TILE(t + 1, 1, u0,u1,u2,u3, 1, 1, v0,v1,v2,v3, VMW(6));
    }
    TILE(28, 1, v0,v1,v2,v3, 1, 1, u0,u1,u2,u3, VMW(6));   // A(31)->v, write A(30)
    TILE(29, 0, u0,u1,u2,u3, 1, 1, v0,v1,v2,v3, VMW(2));   // stage B(31), write A(31)
    TILE(30, 0, u0,u1,u2,u3, 0, 0, u0,u1,u2,u3, VMW(0));   // drain B(31)
    TILE(31, 0, u0,u1,u2,u3, 0, 0, u0,u1,u2,u3, (void)0);

    // epilogue: C/D layout col=lane&15, row=(lane>>4)*4+r
    const size_t outBase = (size_t)nt * 16384 * 256;
    const int ucol = wn * 64 + l15;
    float bv[4];
#pragma unroll
    for (int fn = 0; fn < 4; ++fn) bv[fn] = bias[nt * 256 + ucol + fn * 16];
#pragma unroll
    for (int fm = 0; fm < 8; ++fm) {
        const int m = m0 + wm * 128 + fm * 16 + lg * 4;
#pragma unroll
        for (int r = 0; r < 4; ++r) {
            float* op = out + outBase + (size_t)(m + r) * 256;
#pragma unroll
            for (int fn = 0; fn < 4; ++fn)
                op[ucol + fn * 16] = acc[fm][fn][r] + bv[fn];
        }
    }
}

// ---------------------------------------------------------------------------
extern "C" void kernel_launch(void* const* d_in, const int* in_sizes, int n_in,
                              void* d_out, int out_size, void* d_ws, size_t ws_size,
                              hipStream_t stream) {
    (void)in_sizes; (void)n_in; (void)out_size; (void)ws_size;
    const float* x = (const float*)d_in[0];   // (65536, 256)
    const float* W = (const float*)d_in[1];   // (256, 1024)
    const float* b = (const float*)d_in[2];   // (1024,)
    float* out = (float*)d_out;               // (65536, 256)

    _Float16* Wt = (_Float16*)d_ws;           // 2 MB

    build_wcatT<<<4096, 256, 0, stream>>>(W, Wt);
    ga_gemm<<<256, 512, 0, stream>>>(x, Wt, b, out);
}